// Round 1
// baseline (6543.797 us; speedup 1.0000x reference)
//
#include <hip/hip_runtime.h>
#include <stdint.h>

#define L_SIG   8192
#define T_STEPS 253
#define H1      256
#define H2      128
#define NBATCH  256
#define GRPBLK  16

typedef __attribute__((ext_vector_type(8))) short short8;
typedef __attribute__((ext_vector_type(4))) float f32x4;

__device__ __forceinline__ ushort f2bf(float f){
  uint32_t u = __builtin_bit_cast(uint32_t, f);
  u += 0x7FFFu + ((u >> 16) & 1u);
  return (ushort)(u >> 16);
}
__device__ __forceinline__ float bf2f(ushort h){
  uint32_t u = ((uint32_t)h) << 16;
  return __builtin_bit_cast(float, u);
}
__device__ __forceinline__ float sigm(float x){ return 1.0f / (1.0f + __expf(-x)); }
__device__ __forceinline__ float tanhfast(float x){ return 1.0f - 2.0f / (__expf(2.0f*x) + 1.0f); }

__global__ __launch_bounds__(256, 1)
void encoder_kernel(const float* __restrict__ x,
                    const float* __restrict__ Wih1, const float* __restrict__ Whh1,
                    const float* __restrict__ bih1, const float* __restrict__ bhh1,
                    const float* __restrict__ Wih2, const float* __restrict__ Whh2,
                    const float* __restrict__ bih2, const float* __restrict__ bhh2,
                    float* __restrict__ out,
                    uint32_t* sync_ws,
                    uint32_t* __restrict__ h1buf,
                    uint32_t* __restrict__ h2buf)
{
  // staged A operand: cols [0,128)=x window, [128,384)=h1 prev, [384,512)=h2 prev
  __shared__ ushort sh_hi[16][520];
  __shared__ ushort sh_lo[16][520];
  __shared__ float  sC1[4][16][17];        // [gate tile][batch][dim]
  __shared__ float  sC2[2][2][16][17];     // [tile][khalf][batch][col]

  const int tid  = threadIdx.x;
  const int lane = tid & 63;
  const int wv   = tid >> 6;               // wave 0..3
  const int bid  = blockIdx.x;
  const int grp  = bid >> 4;               // batch group (16 batches)
  const int bi   = bid & 15;               // block in group
  const int B0   = grp * 16;
  const int D1   = bi * 16;                // this block's h1-dim slice
  const int D2   = bi * 8;                 // this block's h2-dim slice

  // ---------------- persistent W fragments in registers (hi/lo split bf16) ---------
  short8 B1h[12], B1l[12];                 // LSTM1: gate tile = wv, rows R1 = wv*256+D1+n
  short8 B2h[6],  B2l[6];                  // LSTM2: tile = wv&1, khalf = wv>>1
  {
    const int nn = lane & 15, p = lane >> 4;
    const int R1 = wv * 256 + D1 + nn;
    #pragma unroll
    for (int kk = 0; kk < 12; ++kk){
      short8 h8, l8;
      #pragma unroll
      for (int j = 0; j < 8; ++j){
        const int k = 32*kk + 8*p + j;
        const float v = (k < 128) ? Wih1[R1*128 + k] : Whh1[R1*256 + (k - 128)];
        const ushort hb = f2bf(v);
        h8[j] = (short)hb;
        l8[j] = (short)f2bf(v - bf2f(hb));
      }
      B1h[kk] = h8; B1l[kk] = l8;
    }
    const int tw = wv & 1, kh = wv >> 1;
    const int rr = tw*16 + nn;                       // row-in-32 = g2*8 + d2
    const int R2 = (rr >> 3) * 128 + D2 + (rr & 7);
    #pragma unroll
    for (int i = 0; i < 6; ++i){
      const int kk2 = 6*kh + i;
      short8 h8, l8;
      #pragma unroll
      for (int j = 0; j < 8; ++j){
        const int k = 32*kk2 + 8*p + j;
        const float v = (k < 256) ? Wih2[R2*256 + k] : Whh2[R2*128 + (k - 256)];
        const ushort hb = f2bf(v);
        h8[j] = (short)hb;
        l8[j] = (short)f2bf(v - bf2f(hb));
      }
      B2h[i] = h8; B2l[i] = l8;
    }
  }

  // biases (combined b_ih + b_hh), per epilogue thread
  const int eb  = tid >> 4, ed  = tid & 15;          // LSTM1 epilogue: (batch, dim)
  const int eb2 = (tid & 127) >> 3, ed2 = tid & 7;   // LSTM2 epilogue (tid<128)
  float bs1[4], bs2[4];
  #pragma unroll
  for (int g = 0; g < 4; ++g){
    bs1[g] = bih1[g*256 + D1 + ed]  + bhh1[g*256 + D1 + ed];
    bs2[g] = bih2[g*128 + D2 + ed2] + bhh2[g*128 + D2 + ed2];
  }

  float c1 = 0.f, c2 = 0.f;                // cell states live in registers

  uint32_t* cnt = sync_ws + grp * 64;      // 256B-spaced per-group barrier slots
  uint32_t* gen = sync_ws + grp * 64 + 16;

  for (int n = 0; n <= T_STEPS; ++n){
    // ---------------- stage A operand (hi/lo planes) ----------------
    {
      const int b  = tid >> 4;
      const int cc = tid & 15;             // 32-col chunk
      const int gb = B0 + b;
      if (cc < 4){                         // x window
        if (n < T_STEPS){
          const float* xp = x + (size_t)gb * L_SIG + 32*n + 32*cc;
          #pragma unroll
          for (int q = 0; q < 4; ++q){
            short8 h8, l8;
            #pragma unroll
            for (int j = 0; j < 8; ++j){
              const float v = xp[8*q + j];
              const ushort hb = f2bf(v);
              h8[j] = (short)hb;
              l8[j] = (short)f2bf(v - bf2f(hb));
            }
            *(short8*)&sh_hi[b][32*cc + 8*q] = h8;
            *(short8*)&sh_lo[b][32*cc + 8*q] = l8;
          }
        } else {
          short8 z = {0,0,0,0,0,0,0,0};
          #pragma unroll
          for (int q = 0; q < 4; ++q){
            *(short8*)&sh_hi[b][32*cc + 8*q] = z;
            *(short8*)&sh_lo[b][32*cc + 8*q] = z;
          }
        }
      } else {                             // packed (hi|lo<<16) h-state buffers
        const bool is1 = (cc < 12);
        const bool zz  = is1 ? (n < 1) : (n < 2);
        const uint32_t* src = is1
            ? (h1buf + (size_t)((n-1)&1) * (NBATCH*H1) + (size_t)gb*H1 + (32*cc - 128))
            : (h2buf + (size_t)((n-1)&1) * (NBATCH*H2) + (size_t)gb*H2 + (32*cc - 384));
        if (!zz){
          #pragma unroll
          for (int q = 0; q < 4; ++q){
            short8 h8, l8;
            #pragma unroll
            for (int j = 0; j < 8; ++j){
              const uint32_t u = src[8*q + j];
              h8[j] = (short)(u & 0xFFFFu);
              l8[j] = (short)(u >> 16);
            }
            *(short8*)&sh_hi[b][32*cc + 8*q] = h8;
            *(short8*)&sh_lo[b][32*cc + 8*q] = l8;
          }
        } else {
          short8 z = {0,0,0,0,0,0,0,0};
          #pragma unroll
          for (int q = 0; q < 4; ++q){
            *(short8*)&sh_hi[b][32*cc + 8*q] = z;
            *(short8*)&sh_lo[b][32*cc + 8*q] = z;
          }
        }
      }
    }
    __syncthreads();

    // ---------------- MFMA phase ----------------
    const int m = lane & 15, p = lane >> 4;
    if (n < T_STEPS){                      // LSTM1 step n: K = [0,384)
      f32x4 hh = {0,0,0,0}, hl = {0,0,0,0}, lh = {0,0,0,0};
      #pragma unroll
      for (int kk = 0; kk < 12; ++kk){
        const short8 ah = *(const short8*)&sh_hi[m][32*kk + 8*p];
        const short8 al = *(const short8*)&sh_lo[m][32*kk + 8*p];
        hh = __builtin_amdgcn_mfma_f32_16x16x32_bf16(ah, B1h[kk], hh, 0, 0, 0);
        hl = __builtin_amdgcn_mfma_f32_16x16x32_bf16(ah, B1l[kk], hl, 0, 0, 0);
        lh = __builtin_amdgcn_mfma_f32_16x16x32_bf16(al, B1h[kk], lh, 0, 0, 0);
      }
      const f32x4 cs = hh + hl + lh;
      #pragma unroll
      for (int r = 0; r < 4; ++r) sC1[wv][4*p + r][m] = cs[r];
    }
    if (n >= 1){                           // LSTM2 step n-1: K = cols [128,512)
      const int tw = wv & 1, kh = wv >> 1;
      f32x4 hh = {0,0,0,0}, hl = {0,0,0,0}, lh = {0,0,0,0};
      #pragma unroll
      for (int i = 0; i < 6; ++i){
        const int kc = 128 + 32*(6*kh + i);
        const short8 ah = *(const short8*)&sh_hi[m][kc + 8*p];
        const short8 al = *(const short8*)&sh_lo[m][kc + 8*p];
        hh = __builtin_amdgcn_mfma_f32_16x16x32_bf16(ah, B2h[i], hh, 0, 0, 0);
        hl = __builtin_amdgcn_mfma_f32_16x16x32_bf16(ah, B2l[i], hl, 0, 0, 0);
        lh = __builtin_amdgcn_mfma_f32_16x16x32_bf16(al, B2h[i], lh, 0, 0, 0);
      }
      const f32x4 cs = hh + hl + lh;
      #pragma unroll
      for (int r = 0; r < 4; ++r) sC2[tw][kh][4*p + r][m] = cs[r];
    }
    __syncthreads();

    // ---------------- elementwise epilogues ----------------
    if (n < T_STEPS){
      float gi = sC1[0][eb][ed] + bs1[0];
      float gf = sC1[1][eb][ed] + bs1[1];
      float gg = sC1[2][eb][ed] + bs1[2];
      float go = sC1[3][eb][ed] + bs1[3];
      c1 = sigm(gf)*c1 + sigm(gi)*tanhfast(gg);
      const float h = sigm(go)*tanhfast(c1);
      const ushort hb = f2bf(h);
      const ushort lb = f2bf(h - bf2f(hb));
      h1buf[(size_t)(n & 1)*(NBATCH*H1) + (size_t)(B0 + eb)*H1 + D1 + ed]
          = (uint32_t)hb | ((uint32_t)lb << 16);
    }
    if (n >= 1 && tid < 128){
      float gi = sC2[0][0][eb2][ed2]   + sC2[0][1][eb2][ed2]   + bs2[0];
      float gf = sC2[0][0][eb2][8+ed2] + sC2[0][1][eb2][8+ed2] + bs2[1];
      float gg = sC2[1][0][eb2][ed2]   + sC2[1][1][eb2][ed2]   + bs2[2];
      float go = sC2[1][0][eb2][8+ed2] + sC2[1][1][eb2][8+ed2] + bs2[3];
      c2 = sigm(gf)*c2 + sigm(gi)*tanhfast(gg);
      const float h = sigm(go)*tanhfast(c2);
      if (n == T_STEPS){
        out[(size_t)(B0 + eb2)*H2 + D2 + ed2] = h;
      } else {
        const ushort hb = f2bf(h);
        const ushort lb = f2bf(h - bf2f(hb));
        h2buf[(size_t)(n & 1)*(NBATCH*H2) + (size_t)(B0 + eb2)*H2 + D2 + ed2]
            = (uint32_t)hb | ((uint32_t)lb << 16);
      }
    }

    // ---------------- group barrier (16 blocks) ----------------
    if (n < T_STEPS){
      __syncthreads();                     // drains all waves' stores (vmcnt 0)
      if (tid == 0){
        __threadfence();                   // release: make block's writes device-visible
        const uint32_t g = __hip_atomic_load(gen, __ATOMIC_RELAXED, __HIP_MEMORY_SCOPE_AGENT);
        const uint32_t a = __hip_atomic_fetch_add(cnt, 1u, __ATOMIC_ACQ_REL, __HIP_MEMORY_SCOPE_AGENT);
        if (a == GRPBLK - 1u){
          __hip_atomic_store(cnt, 0u, __ATOMIC_RELAXED, __HIP_MEMORY_SCOPE_AGENT);
          __hip_atomic_store(gen, g + 1u, __ATOMIC_RELEASE, __HIP_MEMORY_SCOPE_AGENT);
        } else {
          while (__hip_atomic_load(gen, __ATOMIC_RELAXED, __HIP_MEMORY_SCOPE_AGENT) == g){
            __builtin_amdgcn_s_sleep(1);
          }
        }
        __threadfence();                   // acquire: invalidate stale L1/L2 lines
      }
      __syncthreads();
    }
  }
}

extern "C" void kernel_launch(void* const* d_in, const int* in_sizes, int n_in,
                              void* d_out, int out_size, void* d_ws, size_t ws_size,
                              hipStream_t stream)
{
  const float* x    = (const float*)d_in[0];
  const float* Wih1 = (const float*)d_in[1];
  const float* Whh1 = (const float*)d_in[2];
  const float* bih1 = (const float*)d_in[3];
  const float* bhh1 = (const float*)d_in[4];
  const float* Wih2 = (const float*)d_in[5];
  const float* Whh2 = (const float*)d_in[6];
  const float* bih2 = (const float*)d_in[7];
  const float* bhh2 = (const float*)d_in[8];

  uint8_t*  ws    = (uint8_t*)d_ws;
  uint32_t* syncp = (uint32_t*)ws;                                  // 4 KB barrier slots
  uint32_t* h1buf = (uint32_t*)(ws + 4096);                         // 2*256*256*4 = 512 KB
  uint32_t* h2buf = (uint32_t*)(ws + 4096 + 2*NBATCH*H1*4);         // 2*256*128*4 = 256 KB

  hipMemsetAsync(syncp, 0, 4096, stream);
  encoder_kernel<<<dim3(256), dim3(256), 0, stream>>>(
      x, Wih1, Whh1, bih1, bhh1, Wih2, Whh2, bih2, bhh2,
      (float*)d_out, syncp, h1buf, h2buf);
}

// Round 2
// 2505.006 us; speedup vs baseline: 2.6123x; 2.6123x over previous
//
#include <hip/hip_runtime.h>
#include <stdint.h>

#define L_SIG   8192
#define T_STEPS 253
#define H1      256
#define H2      128
#define NBATCH  256
#define GRPBLK  16

typedef __attribute__((ext_vector_type(8))) short short8;
typedef __attribute__((ext_vector_type(4))) float f32x4;

__device__ __forceinline__ ushort f2bf(float f){
  uint32_t u = __builtin_bit_cast(uint32_t, f);
  u += 0x7FFFu + ((u >> 16) & 1u);
  return (ushort)(u >> 16);
}
__device__ __forceinline__ float bf2f(ushort h){
  uint32_t u = ((uint32_t)h) << 16;
  return __builtin_bit_cast(float, u);
}
__device__ __forceinline__ float sigm(float x){ return 1.0f / (1.0f + __expf(-x)); }
__device__ __forceinline__ float tanhfast(float x){ return 1.0f - 2.0f / (__expf(2.0f*x) + 1.0f); }
// 16B-unit LDS swizzle: spreads 64B-stride chunk writes over all 8 bank-slots
__device__ __forceinline__ int swz(int u){ return u ^ ((u >> 3) & 7); }

__global__ __launch_bounds__(256, 1)
void encoder_kernel(const float* __restrict__ x,
                    const float* __restrict__ Wih1, const float* __restrict__ Whh1,
                    const float* __restrict__ bih1, const float* __restrict__ bhh1,
                    const float* __restrict__ Wih2, const float* __restrict__ Whh2,
                    const float* __restrict__ bih2, const float* __restrict__ bhh2,
                    float* __restrict__ out,
                    uint32_t* sync_ws,
                    uint32_t* h1buf,
                    uint32_t* h2buf)
{
  // staged A operand: cols [0,128)=x window, [128,384)=h1 prev, [384,512)=h2 prev
  __shared__ ushort sh_hi[16][520];
  __shared__ ushort sh_lo[16][520];
  __shared__ float  sC1[4][16][17];        // [gate tile][batch][dim]
  __shared__ float  sC2[2][2][16][17];     // [tile][khalf][batch][col]

  const int tid  = threadIdx.x;
  const int lane = tid & 63;
  const int wv   = tid >> 6;               // wave 0..3
  const int bid  = blockIdx.x;
  const int grp  = bid >> 4;               // batch group (16 batches)
  const int bi   = bid & 15;               // block in group
  const int B0   = grp * 16;
  const int D1   = bi * 16;                // this block's h1-dim slice
  const int D2   = bi * 8;                 // this block's h2-dim slice

  // ---------------- persistent W fragments in registers (hi/lo split bf16) ---------
  short8 B1h[12], B1l[12];                 // LSTM1: gate tile = wv, rows R1 = wv*256+D1+n
  short8 B2h[6],  B2l[6];                  // LSTM2: tile = wv&1, khalf = wv>>1
  {
    const int nn = lane & 15, p = lane >> 4;
    const int R1 = wv * 256 + D1 + nn;
    #pragma unroll
    for (int kk = 0; kk < 12; ++kk){
      short8 h8, l8;
      #pragma unroll
      for (int j = 0; j < 8; ++j){
        const int k = 32*kk + 8*p + j;
        const float v = (k < 128) ? Wih1[R1*128 + k] : Whh1[R1*256 + (k - 128)];
        const ushort hb = f2bf(v);
        h8[j] = (short)hb;
        l8[j] = (short)f2bf(v - bf2f(hb));
      }
      B1h[kk] = h8; B1l[kk] = l8;
    }
    const int tw = wv & 1, kh = wv >> 1;
    const int rr = tw*16 + nn;                       // row-in-32 = g2*8 + d2
    const int R2 = (rr >> 3) * 128 + D2 + (rr & 7);
    #pragma unroll
    for (int i = 0; i < 6; ++i){
      const int kk2 = 6*kh + i;
      short8 h8, l8;
      #pragma unroll
      for (int j = 0; j < 8; ++j){
        const int k = 32*kk2 + 8*p + j;
        const float v = (k < 256) ? Wih2[R2*256 + k] : Whh2[R2*128 + (k - 256)];
        const ushort hb = f2bf(v);
        h8[j] = (short)hb;
        l8[j] = (short)f2bf(v - bf2f(hb));
      }
      B2h[i] = h8; B2l[i] = l8;
    }
  }

  // biases (combined b_ih + b_hh), per epilogue thread
  const int eb  = tid >> 4, ed  = tid & 15;          // LSTM1 epilogue: (batch, dim)
  const int eb2 = (tid & 127) >> 3, ed2 = tid & 7;   // LSTM2 epilogue (tid<128)
  float bs1[4], bs2[4];
  #pragma unroll
  for (int g = 0; g < 4; ++g){
    bs1[g] = bih1[g*256 + D1 + ed]  + bhh1[g*256 + D1 + ed];
    bs2[g] = bih2[g*128 + D2 + ed2] + bhh2[g*128 + D2 + ed2];
  }

  float c1 = 0.f, c2 = 0.f;                // cell states live in registers

  uint32_t* slots = sync_ws + grp * 64;    // 16 dword slots per group, 256B spaced

  for (int n = 0; n <= T_STEPS; ++n){
    // ---------------- stage A operand (hi/lo planes) ----------------
    {
      const int b  = tid >> 4;
      const int cc = tid & 15;             // 32-col chunk
      const int gb = B0 + b;
      if (cc < 4){                         // x window (read-only input, L1-cached)
        if (n < T_STEPS){
          const float* xp = x + (size_t)gb * L_SIG + 32*n + 32*cc;
          #pragma unroll
          for (int q = 0; q < 4; ++q){
            short8 h8, l8;
            #pragma unroll
            for (int j = 0; j < 8; ++j){
              const float v = xp[8*q + j];
              const ushort hb = f2bf(v);
              h8[j] = (short)hb;
              l8[j] = (short)f2bf(v - bf2f(hb));
            }
            const int u = swz(4*cc + q);
            *(short8*)&sh_hi[b][8*u] = h8;
            *(short8*)&sh_lo[b][8*u] = l8;
          }
        } else {
          short8 z = {0,0,0,0,0,0,0,0};
          #pragma unroll
          for (int q = 0; q < 4; ++q){
            const int u = swz(4*cc + q);
            *(short8*)&sh_hi[b][8*u] = z;
            *(short8*)&sh_lo[b][8*u] = z;
          }
        }
      } else {                             // packed (hi|lo<<16) h-state, MALL-coherent
        const bool is1 = (cc < 12);
        const bool zz  = is1 ? (n < 1) : (n < 2);
        const uint32_t* src = is1
            ? (h1buf + (size_t)((n-1)&1) * (NBATCH*H1) + (size_t)gb*H1 + (32*cc - 128))
            : (h2buf + (size_t)((n-1)&1) * (NBATCH*H2) + (size_t)gb*H2 + (32*cc - 384));
        if (!zz){
          uint32_t uu[32];
          #pragma unroll
          for (int j = 0; j < 32; ++j)
            uu[j] = __hip_atomic_load(&src[j], __ATOMIC_RELAXED, __HIP_MEMORY_SCOPE_AGENT);
          #pragma unroll
          for (int q = 0; q < 4; ++q){
            short8 h8, l8;
            #pragma unroll
            for (int j = 0; j < 8; ++j){
              const uint32_t u32v = uu[8*q + j];
              h8[j] = (short)(u32v & 0xFFFFu);
              l8[j] = (short)(u32v >> 16);
            }
            const int u = swz(4*cc + q);
            *(short8*)&sh_hi[b][8*u] = h8;
            *(short8*)&sh_lo[b][8*u] = l8;
          }
        } else {
          short8 z = {0,0,0,0,0,0,0,0};
          #pragma unroll
          for (int q = 0; q < 4; ++q){
            const int u = swz(4*cc + q);
            *(short8*)&sh_hi[b][8*u] = z;
            *(short8*)&sh_lo[b][8*u] = z;
          }
        }
      }
    }
    __syncthreads();

    // ---------------- MFMA phase ----------------
    const int m = lane & 15, p = lane >> 4;
    if (n < T_STEPS){                      // LSTM1 step n: K = [0,384)
      f32x4 hh = {0,0,0,0}, hl = {0,0,0,0}, lh = {0,0,0,0};
      #pragma unroll
      for (int kk = 0; kk < 12; ++kk){
        const int u = swz(4*kk + p);
        const short8 ah = *(const short8*)&sh_hi[m][8*u];
        const short8 al = *(const short8*)&sh_lo[m][8*u];
        hh = __builtin_amdgcn_mfma_f32_16x16x32_bf16(ah, B1h[kk], hh, 0, 0, 0);
        hl = __builtin_amdgcn_mfma_f32_16x16x32_bf16(ah, B1l[kk], hl, 0, 0, 0);
        lh = __builtin_amdgcn_mfma_f32_16x16x32_bf16(al, B1h[kk], lh, 0, 0, 0);
      }
      const f32x4 cs = hh + hl + lh;
      #pragma unroll
      for (int r = 0; r < 4; ++r) sC1[wv][4*p + r][m] = cs[r];
    }
    if (n >= 1){                           // LSTM2 step n-1: K = cols [128,512)
      const int tw = wv & 1, kh = wv >> 1;
      f32x4 hh = {0,0,0,0}, hl = {0,0,0,0}, lh = {0,0,0,0};
      #pragma unroll
      for (int i = 0; i < 6; ++i){
        const int u = swz(16 + 4*(6*kh + i) + p);
        const short8 ah = *(const short8*)&sh_hi[m][8*u];
        const short8 al = *(const short8*)&sh_lo[m][8*u];
        hh = __builtin_amdgcn_mfma_f32_16x16x32_bf16(ah, B2h[i], hh, 0, 0, 0);
        hl = __builtin_amdgcn_mfma_f32_16x16x32_bf16(ah, B2l[i], hl, 0, 0, 0);
        lh = __builtin_amdgcn_mfma_f32_16x16x32_bf16(al, B2h[i], lh, 0, 0, 0);
      }
      const f32x4 cs = hh + hl + lh;
      #pragma unroll
      for (int r = 0; r < 4; ++r) sC2[tw][kh][4*p + r][m] = cs[r];
    }
    __syncthreads();

    // ---------------- elementwise epilogues ----------------
    if (n < T_STEPS){
      float gi = sC1[0][eb][ed] + bs1[0];
      float gf = sC1[1][eb][ed] + bs1[1];
      float gg = sC1[2][eb][ed] + bs1[2];
      float go = sC1[3][eb][ed] + bs1[3];
      c1 = sigm(gf)*c1 + sigm(gi)*tanhfast(gg);
      const float h = sigm(go)*tanhfast(c1);
      const ushort hb = f2bf(h);
      const ushort lb = f2bf(h - bf2f(hb));
      __hip_atomic_store(
          &h1buf[(size_t)(n & 1)*(NBATCH*H1) + (size_t)(B0 + eb)*H1 + D1 + ed],
          (uint32_t)hb | ((uint32_t)lb << 16),
          __ATOMIC_RELAXED, __HIP_MEMORY_SCOPE_AGENT);
    }
    if (n >= 1 && tid < 128){
      float gi = sC2[0][0][eb2][ed2]   + sC2[0][1][eb2][ed2]   + bs2[0];
      float gf = sC2[0][0][eb2][8+ed2] + sC2[0][1][eb2][8+ed2] + bs2[1];
      float gg = sC2[1][0][eb2][ed2]   + sC2[1][1][eb2][ed2]   + bs2[2];
      float go = sC2[1][0][eb2][8+ed2] + sC2[1][1][eb2][8+ed2] + bs2[3];
      c2 = sigm(gf)*c2 + sigm(gi)*tanhfast(gg);
      const float h = sigm(go)*tanhfast(c2);
      if (n == T_STEPS){
        out[(size_t)(B0 + eb2)*H2 + D2 + ed2] = h;
      } else {
        const ushort hb = f2bf(h);
        const ushort lb = f2bf(h - bf2f(hb));
        __hip_atomic_store(
            &h2buf[(size_t)(n & 1)*(NBATCH*H2) + (size_t)(B0 + eb2)*H2 + D2 + ed2],
            (uint32_t)hb | ((uint32_t)lb << 16),
            __ATOMIC_RELAXED, __HIP_MEMORY_SCOPE_AGENT);
      }
    }

    // ---------------- group barrier (16 blocks, slot array, no fences) ----------
    if (n < T_STEPS){
      __syncthreads();                     // drains vmcnt: all h-stores at MALL
      if (tid == 0){
        __hip_atomic_store(&slots[bi], (uint32_t)(n + 1),
                           __ATOMIC_RELAXED, __HIP_MEMORY_SCOPE_AGENT);
      }
      if (tid < 64){                       // wave0: poll all 16 slots in one load
        const uint32_t tgt = (uint32_t)(n + 1);
        while (true){
          const uint32_t v = __hip_atomic_load(&slots[lane & 15],
                                               __ATOMIC_RELAXED, __HIP_MEMORY_SCOPE_AGENT);
          if (__all(v >= tgt)) break;
          __builtin_amdgcn_s_sleep(1);
        }
      }
      __syncthreads();
    }
  }
}

extern "C" void kernel_launch(void* const* d_in, const int* in_sizes, int n_in,
                              void* d_out, int out_size, void* d_ws, size_t ws_size,
                              hipStream_t stream)
{
  const float* x    = (const float*)d_in[0];
  const float* Wih1 = (const float*)d_in[1];
  const float* Whh1 = (const float*)d_in[2];
  const float* bih1 = (const float*)d_in[3];
  const float* bhh1 = (const float*)d_in[4];
  const float* Wih2 = (const float*)d_in[5];
  const float* Whh2 = (const float*)d_in[6];
  const float* bih2 = (const float*)d_in[7];
  const float* bhh2 = (const float*)d_in[8];

  uint8_t*  ws    = (uint8_t*)d_ws;
  uint32_t* syncp = (uint32_t*)ws;                                  // 4 KB barrier slots
  uint32_t* h1buf = (uint32_t*)(ws + 4096);                         // 2*256*256*4 = 512 KB
  uint32_t* h2buf = (uint32_t*)(ws + 4096 + 2*NBATCH*H1*4);         // 2*256*128*4 = 256 KB

  hipMemsetAsync(syncp, 0, 4096, stream);
  encoder_kernel<<<dim3(256), dim3(256), 0, stream>>>(
      x, Wih1, Whh1, bih1, bhh1, Wih2, Whh2, bih2, bhh2,
      (float*)d_out, syncp, h1buf, h2buf);
}

// Round 3
// 759.734 us; speedup vs baseline: 8.6133x; 3.2972x over previous
//
#include <hip/hip_runtime.h>
#include <stdint.h>

#define L_SIG   8192
#define T_STEPS 253
#define H1      256
#define H2      128
#define NBATCH  256

typedef __attribute__((ext_vector_type(8))) short short8;
typedef __attribute__((ext_vector_type(4))) float f32x4;
typedef unsigned int uint32x4 __attribute__((ext_vector_type(4)));
typedef unsigned int uint32x2 __attribute__((ext_vector_type(2)));

__device__ __forceinline__ ushort f2bf(float f){
  uint32_t u = __builtin_bit_cast(uint32_t, f);
  u += 0x7FFFu + ((u >> 16) & 1u);
  return (ushort)(u >> 16);
}
__device__ __forceinline__ float bf2f(ushort h){
  uint32_t u = ((uint32_t)h) << 16;
  return __builtin_bit_cast(float, u);
}
__device__ __forceinline__ float sigm(float x){ return 1.0f / (1.0f + __expf(-x)); }
__device__ __forceinline__ float tanhfast(float x){ return 1.0f - 2.0f / (__expf(2.0f*x) + 1.0f); }
// 16B-unit swizzle within sh rows (bijective per 8-unit stripe)
__device__ __forceinline__ int swz(int u){ return u ^ ((u >> 3) & 7); }
// agent-coherent 16B load (bypasses L1/L2, reads MALL); NO waitcnt — caller drains
__device__ __forceinline__ void load_coh(uint32x4& r, const unsigned int* p){
  asm volatile("global_load_dwordx4 %0, %1, off sc0 sc1" : "=&v"(r) : "v"(p));
}

__global__ __launch_bounds__(256, 1)
void encoder_kernel(const float* __restrict__ x,
                    const float* __restrict__ Wih1, const float* __restrict__ Whh1,
                    const float* __restrict__ bih1, const float* __restrict__ bhh1,
                    const float* __restrict__ Wih2, const float* __restrict__ Whh2,
                    const float* __restrict__ bih2, const float* __restrict__ bhh2,
                    float* __restrict__ out,
                    unsigned int* sync_ws,
                    unsigned int* h1buf,
                    unsigned int* h2buf)
{
  // staged A operand rows: 16 batches x 520 ushort cols.
  // logical cols [0,128)=x window, [128,384)=h1 prev, [384,512)=h2 prev-prev
  // stored with 16B-unit swizzle: ushort col c -> unit u=c>>3 placed at 8*swz(u)
  __shared__ ushort sh_hi[16][520];
  __shared__ ushort sh_lo[16][520];
  __shared__ float  sC1[4][16][20];        // [gate][batch][dim]
  __shared__ float  sC2[2][2][16][20];     // [tile][khalf][batch][col]

  const int tid  = threadIdx.x;
  const int lane = tid & 63;
  const int wv   = tid >> 6;               // wave 0..3
  const int bid  = blockIdx.x;
  // XCD-aware grouping (perf-only): blocks with equal bid&7 share an XCD.
  const int grp = 2 * (bid & 7) + (bid >> 7);   // 16 groups
  const int bi  = (bid & 127) >> 3;             // block-in-group 0..15
  const int B0  = grp * 16;
  const int D1  = bi * 16;                 // h1-dim slice
  const int D2  = bi * 8;                  // h2-dim slice

  // ---------------- persistent W fragments in registers (hi/lo split bf16) --------
  short8 B1h[12], B1l[12];                 // LSTM1: gate = wv, rows R1 = wv*256+D1+nn
  short8 B2h[6],  B2l[6];                  // LSTM2: tile = wv&1, khalf = wv>>1
  {
    const int nn = lane & 15, p = lane >> 4;
    const int R1 = wv * 256 + D1 + nn;
    #pragma unroll
    for (int kk = 0; kk < 12; ++kk){
      short8 h8, l8;
      #pragma unroll
      for (int j = 0; j < 8; ++j){
        const int k = 32*kk + 8*p + j;
        const float v = (k < 128) ? Wih1[R1*128 + k] : Whh1[R1*256 + (k - 128)];
        const ushort hb = f2bf(v);
        h8[j] = (short)hb;
        l8[j] = (short)f2bf(v - bf2f(hb));
      }
      B1h[kk] = h8; B1l[kk] = l8;
    }
    const int tw = wv & 1, kh = wv >> 1;
    const int rr = tw*16 + nn;                       // row-in-32 = g2*8 + d2
    const int R2 = (rr >> 3) * 128 + D2 + (rr & 7);
    #pragma unroll
    for (int i = 0; i < 6; ++i){
      const int kk2 = 6*kh + i;
      short8 h8, l8;
      #pragma unroll
      for (int j = 0; j < 8; ++j){
        const int k = 32*kk2 + 8*p + j;
        const float v = (k < 256) ? Wih2[R2*256 + k] : Whh2[R2*128 + (k - 256)];
        const ushort hb = f2bf(v);
        h8[j] = (short)hb;
        l8[j] = (short)f2bf(v - bf2f(hb));
      }
      B2h[i] = h8; B2l[i] = l8;
    }
  }

  // biases (b_ih + b_hh) per epilogue thread
  const int eb  = tid >> 4, ed  = tid & 15;          // LSTM1 epilogue (batch, dim)
  const int eb2 = (tid & 127) >> 3, ed2 = tid & 7;   // LSTM2 epilogue (tid<128)
  float bs1[4], bs2[4];
  #pragma unroll
  for (int g = 0; g < 4; ++g){
    bs1[g] = bih1[g*256 + D1 + ed]  + bhh1[g*256 + D1 + ed];
    bs2[g] = bih2[g*128 + D2 + ed2] + bhh2[g*128 + D2 + ed2];
  }

  float c1 = 0.f, c2 = 0.f;                // cell states in registers
  unsigned int* slots = sync_ws + grp * 64;

  // ---- coalesced x-window stage: 16 batches x 128 cols, 8 floats/thread ----
  auto stageX = [&](int wn){
    const int bx = tid >> 4, cx = tid & 15;
    const float* xp = x + (size_t)(B0 + bx) * L_SIG + 32*wn + 8*cx;
    const float4 v0 = *(const float4*)xp;
    const float4 v1 = *(const float4*)(xp + 4);
    float f[8] = {v0.x, v0.y, v0.z, v0.w, v1.x, v1.y, v1.z, v1.w};
    union { ushort s[8]; uint32x4 v; } H, L;
    #pragma unroll
    for (int j = 0; j < 8; ++j){
      const ushort hb = f2bf(f[j]);
      H.s[j] = hb;
      L.s[j] = f2bf(f[j] - bf2f(hb));
    }
    const int u = swz(cx);
    *(uint32x4*)&sh_hi[bx][8*u] = H.v;
    *(uint32x4*)&sh_lo[bx][8*u] = L.v;
  };

  // unpack one coherent 16B chunk (4 packed hi|lo values) into LDS
  auto wrState = [&](uint32x4 q, int b, int us){
    union { ushort s[4]; uint32x2 v; } Hh, Ll;
    #pragma unroll
    for (int k = 0; k < 4; ++k){
      const unsigned int u = q[k];
      Hh.s[k] = (ushort)(u & 0xFFFFu);
      Ll.s[k] = (ushort)(u >> 16);
    }
    *(uint32x2*)&sh_hi[b][us] = Hh.v;
    *(uint32x2*)&sh_lo[b][us] = Ll.v;
  };

  // ---- coalesced coherent state load: h1(n) [parity n&1], h2(n-1) [(n-1)&1] ----
  auto stageState = [&](int n){
    const unsigned int* h1p = h1buf + (size_t)(n & 1)*(NBATCH*H1) + (size_t)B0*H1 + 4*tid;
    uint32x4 q0, q1, q2, q3, q4, q5;
    load_coh(q0, h1p);
    load_coh(q1, h1p + 1024);
    load_coh(q2, h1p + 2048);
    load_coh(q3, h1p + 3072);
    const bool h2v = (n >= 1);
    if (h2v){
      const unsigned int* h2p = h2buf + (size_t)((n-1) & 1)*(NBATCH*H2) + (size_t)B0*H2 + 4*tid;
      load_coh(q4, h2p);
      load_coh(q5, h2p + 1024);
    }
    asm volatile("s_waitcnt vmcnt(0)" ::: "memory");
    __builtin_amdgcn_sched_barrier(0);
    {
      const int t6 = tid & 63;
      const int us = 8*swz(16 + (t6 >> 1)) + 4*(t6 & 1);   // h1 cols 128+4*(t&63)
      const int b0r = tid >> 6;
      wrState(q0, b0r + 0,  us);
      wrState(q1, b0r + 4,  us);
      wrState(q2, b0r + 8,  us);
      wrState(q3, b0r + 12, us);
    }
    {
      const int t5 = tid & 31;
      const int us = 8*swz(48 + (t5 >> 1)) + 4*(t5 & 1);   // h2 cols 384+4*(t&31)
      const int b0r = tid >> 5;
      if (h2v){
        wrState(q4, b0r + 0, us);
        wrState(q5, b0r + 8, us);
      } else {
        uint32x2 z = {0, 0};
        *(uint32x2*)&sh_hi[b0r + 0][us] = z; *(uint32x2*)&sh_lo[b0r + 0][us] = z;
        *(uint32x2*)&sh_hi[b0r + 8][us] = z; *(uint32x2*)&sh_lo[b0r + 8][us] = z;
      }
    }
  };

  // ---------------- prologue: zero state region, stage x(0) ----------------
  for (int i = tid; i < 16*384; i += 256){
    const int b = i / 384, c = 128 + (i % 384);
    const int us = 8*swz(c >> 3) + (c & 7);
    sh_hi[b][us] = 0; sh_lo[b][us] = 0;
  }
  stageX(0);
  __syncthreads();

  for (int n = 0; n <= T_STEPS; ++n){
    // ---------------- MFMA phase ----------------
    const int m = lane & 15, p = lane >> 4;
    if (n < T_STEPS){                      // LSTM1 step n: K-cols [0,384)
      f32x4 hh = {0,0,0,0}, hl = {0,0,0,0}, lh = {0,0,0,0};
      #pragma unroll
      for (int kk = 0; kk < 12; ++kk){
        const int u = swz(4*kk + p);
        const short8 ah = *(const short8*)&sh_hi[m][8*u];
        const short8 al = *(const short8*)&sh_lo[m][8*u];
        hh = __builtin_amdgcn_mfma_f32_16x16x32_bf16(ah, B1h[kk], hh, 0, 0, 0);
        hl = __builtin_amdgcn_mfma_f32_16x16x32_bf16(ah, B1l[kk], hl, 0, 0, 0);
        lh = __builtin_amdgcn_mfma_f32_16x16x32_bf16(al, B1h[kk], lh, 0, 0, 0);
      }
      const f32x4 cs = hh + hl + lh;
      #pragma unroll
      for (int r = 0; r < 4; ++r) sC1[wv][4*p + r][m] = cs[r];
    }
    if (n >= 1){                           // LSTM2 step n-1: K-cols [128,512)
      const int tw = wv & 1, kh = wv >> 1;
      f32x4 hh = {0,0,0,0}, hl = {0,0,0,0}, lh = {0,0,0,0};
      #pragma unroll
      for (int i = 0; i < 6; ++i){
        const int u = swz(16 + 4*(6*kh + i) + p);
        const short8 ah = *(const short8*)&sh_hi[m][8*u];
        const short8 al = *(const short8*)&sh_lo[m][8*u];
        hh = __builtin_amdgcn_mfma_f32_16x16x32_bf16(ah, B2h[i], hh, 0, 0, 0);
        hl = __builtin_amdgcn_mfma_f32_16x16x32_bf16(ah, B2l[i], hl, 0, 0, 0);
        lh = __builtin_amdgcn_mfma_f32_16x16x32_bf16(al, B2h[i], lh, 0, 0, 0);
      }
      const f32x4 cs = hh + hl + lh;
      #pragma unroll
      for (int r = 0; r < 4; ++r) sC2[tw][kh][4*p + r][m] = cs[r];
    }
    __syncthreads();                       // (1) sC ready

    // ---------------- elementwise epilogues + publish ----------------
    if (n < T_STEPS){
      float gi = sC1[0][eb][ed] + bs1[0];
      float gf = sC1[1][eb][ed] + bs1[1];
      float gg = sC1[2][eb][ed] + bs1[2];
      float go = sC1[3][eb][ed] + bs1[3];
      c1 = sigm(gf)*c1 + sigm(gi)*tanhfast(gg);
      const float h = sigm(go)*tanhfast(c1);
      const ushort hb = f2bf(h);
      const ushort lb = f2bf(h - bf2f(hb));
      __hip_atomic_store(
          &h1buf[(size_t)(n & 1)*(NBATCH*H1) + (size_t)(B0 + eb)*H1 + D1 + ed],
          (uint32_t)hb | ((uint32_t)lb << 16),
          __ATOMIC_RELAXED, __HIP_MEMORY_SCOPE_AGENT);
    }
    if (n >= 1 && tid < 128){
      float gi = sC2[0][0][eb2][ed2]   + sC2[0][1][eb2][ed2]   + bs2[0];
      float gf = sC2[0][0][eb2][8+ed2] + sC2[0][1][eb2][8+ed2] + bs2[1];
      float gg = sC2[1][0][eb2][ed2]   + sC2[1][1][eb2][ed2]   + bs2[2];
      float go = sC2[1][0][eb2][8+ed2] + sC2[1][1][eb2][8+ed2] + bs2[3];
      c2 = sigm(gf)*c2 + sigm(gi)*tanhfast(gg);
      const float h = sigm(go)*tanhfast(c2);
      if (n == T_STEPS){
        out[(size_t)(B0 + eb2)*H2 + D2 + ed2] = h;
      } else {
        const ushort hb = f2bf(h);
        const ushort lb = f2bf(h - bf2f(hb));
        __hip_atomic_store(
            &h2buf[(size_t)((n-1) & 1)*(NBATCH*H2) + (size_t)(B0 + eb2)*H2 + D2 + ed2],
            (uint32_t)hb | ((uint32_t)lb << 16),
            __ATOMIC_RELAXED, __HIP_MEMORY_SCOPE_AGENT);
      }
    }

    // ---------------- publish barrier + prefetch next operands ----------------
    if (n < T_STEPS){
      __syncthreads();                     // (2) drain payload stores (vmcnt 0)
      if (tid == 0){
        __hip_atomic_store(&slots[bi], (unsigned int)(n + 1),
                           __ATOMIC_RELAXED, __HIP_MEMORY_SCOPE_AGENT);
      }
      if (n + 1 < T_STEPS) stageX(n + 1);  // barrier-independent, overlaps poll
      if (wv == 0){                        // wave0 polls all 16 slots (one line)
        const unsigned int tgt = (unsigned int)(n + 1);
        while (true){
          const unsigned int v = __hip_atomic_load(&slots[lane & 15],
                                                   __ATOMIC_RELAXED, __HIP_MEMORY_SCOPE_AGENT);
          if (__all(v >= tgt)) break;
          __builtin_amdgcn_s_sleep(1);
        }
      }
      __syncthreads();                     // (3) barrier established
      stageState(n);                       // coalesced coherent loads -> LDS
      __syncthreads();                     // (4) operands staged for iter n+1
    }
  }
}

extern "C" void kernel_launch(void* const* d_in, const int* in_sizes, int n_in,
                              void* d_out, int out_size, void* d_ws, size_t ws_size,
                              hipStream_t stream)
{
  const float* x    = (const float*)d_in[0];
  const float* Wih1 = (const float*)d_in[1];
  const float* Whh1 = (const float*)d_in[2];
  const float* bih1 = (const float*)d_in[3];
  const float* bhh1 = (const float*)d_in[4];
  const float* Wih2 = (const float*)d_in[5];
  const float* Whh2 = (const float*)d_in[6];
  const float* bih2 = (const float*)d_in[7];
  const float* bhh2 = (const float*)d_in[8];

  uint8_t*      ws    = (uint8_t*)d_ws;
  unsigned int* syncp = (unsigned int*)ws;                          // 4 KB barrier slots
  unsigned int* h1buf = (unsigned int*)(ws + 4096);                 // 512 KB
  unsigned int* h2buf = (unsigned int*)(ws + 4096 + 2*NBATCH*H1*4); // 256 KB

  hipMemsetAsync(syncp, 0, 4096, stream);
  encoder_kernel<<<dim3(256), dim3(256), 0, stream>>>(
      x, Wih1, Whh1, bih1, bhh1, Wih2, Whh2, bih2, bhh2,
      (float*)d_out, syncp, h1buf, h2buf);
}